// Round 8
// baseline (180.370 us; speedup 1.0000x reference)
//
#include <hip/hip_runtime.h>

// BurstSnn: 32-step burst-encoder + 2-layer LIF SNN, B=16384, D=187, H=50, C=5.
// One wave per batch element; 16 waves/block share one LDS weight copy.
// R7: layer-1 gather per t-pair picks one of two exact paths:
//  - DENSE (nmax>=24; statically this is pair t=0/1, ~87%/62% spike density):
//    unconditional stream d=0..31 over all 6 groups, ds_read_b64 with
//    immediate offsets off one base (no addr VALU, no scan chain),
//    value folded via fmaf(w, sel in {0,1}, c) — exact (x*1.0 and +0.0).
//  - SCAN (sparse): single pass, 6 concurrent group-streams (6 independent
//    ds_read_b64 in flight), trips = max popcount over the 6 groups,
//    exhausted streams read the zero row (exact no-op).
// Half-wave t/t+1 pairing, float2 rows {h=l, h=l+25}, zero rows at rd=33g
// retained from R4-R6. Rows padded to 198 so dense reads stay in-bounds.
// Counts output depends only on the encoder (exact); spike output keeps
// ascending-d partials merged in fixed ascending order.

constexpr int D = 187;
constexpr int H = 50;
constexpr int C = 5;
constexpr int T = 32;
constexpr int WPB = 16;        // waves per block
constexpr int ROWS1 = 198;     // rd = 33*(d>>5) + (d&31) + 1; rd=33g zero; padded
constexpr int RS = 64;         // floats per Wt1 row (256 B)

__device__ __forceinline__ unsigned long long pin_v64(unsigned long long m) {
    unsigned int lo = (unsigned int)m, hi = (unsigned int)(m >> 32);
    asm("" : "+v"(lo));
    asm("" : "+v"(hi));
    return ((unsigned long long)hi << 32) | lo;
}
__device__ __forceinline__ int v_ffbl(unsigned int m) {  // -1 when m == 0
    int r;
    asm("v_ffbl_b32 %0, %1" : "=v"(r) : "v"(m));
    return r;
}

__global__ __launch_bounds__(1024, 8)
void burst_snn_kernel(const float* __restrict__ x,
                      const float* __restrict__ W1,
                      const float* __restrict__ W2,
                      float* __restrict__ out, int B) {
    // Row layout (split-pair): floats {2l,2l+1} = {W[h=l], W[h=l+25]}, l<25; rest 0.
    __shared__ float Wt1[ROWS1 * RS];   // 12672 floats = 49.5 KB
    __shared__ float Wt2[512];          // row rh = h+1 (8 floats each), rh=0 zeros

    const int tid = threadIdx.x;
    for (int idx = tid; idx < ROWS1 * RS; idx += 1024) {
        int rd = idx >> 6, j = idx & 63;
        int g = rd / 33;
        if (g > 5) g = 5;
        bool zrow = (rd == 33 * g);
        int d = rd - 1 - g;
        int l = j >> 1;
        int h = (j & 1) ? (l + 25) : l;
        float v = 0.f;
        if (!zrow && l < 25 && d >= 0 && d < D) v = W1[h * D + d];
        Wt1[idx] = v;
    }
    if (tid < 512) {
        int rh = tid >> 3, c = tid & 7;
        float v = 0.f;
        if (rh >= 1 && rh <= H && c < C) v = W2[c * H + (rh - 1)];
        Wt2[tid] = v;
    }
    __syncthreads();

    const int lane = tid & 63;
    const int b = blockIdx.x * WPB + (tid >> 6);
    const bool active = b < B;
    const bool isLo = lane < 32;
    const int laneHalf = lane & 31;
    const int laneOff2 = laneHalf * 2;   // float2 slot within a Wt1 row

    // Per-group base pointers, +1 row folded in: addr(f) = base + f*64 floats;
    // f = -1 (exhausted scan stream) -> zero row 33g. Dense path: f = d in 0..31.
    const float* gbase0 = Wt1 + ((33 * 0 + 1) << 6) + laneOff2;
    const float* gbase1 = Wt1 + ((33 * 1 + 1) << 6) + laneOff2;
    const float* gbase2 = Wt1 + ((33 * 2 + 1) << 6) + laneOff2;
    const float* gbase3 = Wt1 + ((33 * 3 + 1) << 6) + laneOff2;
    const float* gbase4 = Wt1 + ((33 * 4 + 1) << 6) + laneOff2;
    const float* gbase5 = Wt1 + ((33 * 5 + 1) << 6) + laneOff2;

    // Encoder registers: dims lane, lane+64, lane+128 (3rd valid for lane<59)
    float r0 = 0.f, r1 = 0.f, r2 = 0.f;
    if (active) {
        const float* xb = x + (size_t)b * D;
        r0 = xb[lane];
        r1 = xb[64 + lane];
        if (lane < D - 128) r2 = xb[128 + lane];
    }
    float th0 = 0.125f, th1 = 0.125f, th2 = 0.125f;
    float mem1x = 0.f, mem1y = 0.f;  // lanes 0..24: h = lane / h = lane+25
    float mem2 = 0.f;                // lanes 0..4: c = lane
    int cnt = 0;

    float* outSpk = out;                     // [T][B][C]
    float* outCnt = out + (size_t)T * B * C; // [B]

    unsigned int ga[6], gb[6];

    for (int t = 0; t < T; t += 2) {
        // --- two encoder steps (exact fp32 sequence), masks for t and t+1
        {
            bool s0 = r0 >= th0, s1 = r1 >= th1, s2 = r2 >= th2;
            r0 -= s0 ? th0 : 0.f; th0 = s0 ? th0 + th0 : 0.125f;
            r1 -= s1 ? th1 : 0.f; th1 = s1 ? th1 + th1 : 0.125f;
            r2 -= s2 ? th2 : 0.f; th2 = s2 ? th2 + th2 : 0.125f;
            cnt += (int)s0 + (int)s1 + (int)s2;
            unsigned long long B0 = __ballot(s0), B1 = __ballot(s1), B2 = __ballot(s2);
            ga[0] = (unsigned int)B0; ga[1] = (unsigned int)(B0 >> 32);
            ga[2] = (unsigned int)B1; ga[3] = (unsigned int)(B1 >> 32);
            ga[4] = (unsigned int)B2; ga[5] = (unsigned int)(B2 >> 32);
        }
        {
            bool s0 = r0 >= th0, s1 = r1 >= th1, s2 = r2 >= th2;
            r0 -= s0 ? th0 : 0.f; th0 = s0 ? th0 + th0 : 0.125f;
            r1 -= s1 ? th1 : 0.f; th1 = s1 ? th1 + th1 : 0.125f;
            r2 -= s2 ? th2 : 0.f; th2 = s2 ? th2 + th2 : 0.125f;
            cnt += (int)s0 + (int)s1 + (int)s2;
            unsigned long long B0 = __ballot(s0), B1 = __ballot(s1), B2 = __ballot(s2);
            gb[0] = (unsigned int)B0; gb[1] = (unsigned int)(B0 >> 32);
            gb[2] = (unsigned int)B1; gb[3] = (unsigned int)(B1 >> 32);
            gb[4] = (unsigned int)B2; gb[5] = (unsigned int)(B2 >> 32);
        }

        // Per-group trip counts (wave-uniform, SALU)
        int n0 = __popc(ga[0]) > __popc(gb[0]) ? __popc(ga[0]) : __popc(gb[0]);
        int n1 = __popc(ga[1]) > __popc(gb[1]) ? __popc(ga[1]) : __popc(gb[1]);
        int n2g = __popc(ga[2]) > __popc(gb[2]) ? __popc(ga[2]) : __popc(gb[2]);
        int n3 = __popc(ga[3]) > __popc(gb[3]) ? __popc(ga[3]) : __popc(gb[3]);
        int n4 = __popc(ga[4]) > __popc(gb[4]) ? __popc(ga[4]) : __popc(gb[4]);
        int n5 = __popc(ga[5]) > __popc(gb[5]) ? __popc(ga[5]) : __popc(gb[5]);
        int nmax = n0;
        nmax = nmax > n1 ? nmax : n1;
        nmax = nmax > n2g ? nmax : n2g;
        nmax = nmax > n3 ? nmax : n3;
        nmax = nmax > n4 ? nmax : n4;
        nmax = nmax > n5 ? nmax : n5;

        float cx0 = 0.f, cy0 = 0.f, cx1 = 0.f, cy1 = 0.f, cx2 = 0.f, cy2 = 0.f;
        float cx3 = 0.f, cy3 = 0.f, cx4 = 0.f, cy4 = 0.f, cx5 = 0.f, cy5 = 0.f;

        // Per-lane masks: lanes<32 step t, lanes>=32 step t+1
        unsigned int vm0 = isLo ? ga[0] : gb[0];
        unsigned int vm1 = isLo ? ga[1] : gb[1];
        unsigned int vm2 = isLo ? ga[2] : gb[2];
        unsigned int vm3 = isLo ? ga[3] : gb[3];
        unsigned int vm4 = isLo ? ga[4] : gb[4];
        unsigned int vm5 = isLo ? ga[5] : gb[5];

        if (nmax >= 24) {
            // --- DENSE path: stream all 32 rows of every group; sel in {0,1}
            // keeps fp32 results identical to add-if-set (x*1.0, +0.0 exact).
#pragma unroll
            for (int d = 0; d < 32; ++d) {
                float2 w0 = *(const float2*)(gbase0 + (d << 6));
                float2 w1 = *(const float2*)(gbase1 + (d << 6));
                float2 w2 = *(const float2*)(gbase2 + (d << 6));
                float2 w3 = *(const float2*)(gbase3 + (d << 6));
                float2 w4 = *(const float2*)(gbase4 + (d << 6));
                float2 w5 = *(const float2*)(gbase5 + (d << 6));
                float s0f = (vm0 >> d) & 1u ? 1.0f : 0.0f;
                float s1f = (vm1 >> d) & 1u ? 1.0f : 0.0f;
                float s2f = (vm2 >> d) & 1u ? 1.0f : 0.0f;
                float s3f = (vm3 >> d) & 1u ? 1.0f : 0.0f;
                float s4f = (vm4 >> d) & 1u ? 1.0f : 0.0f;
                float s5f = (vm5 >> d) & 1u ? 1.0f : 0.0f;
                cx0 = fmaf(w0.x, s0f, cx0); cy0 = fmaf(w0.y, s0f, cy0);
                cx1 = fmaf(w1.x, s1f, cx1); cy1 = fmaf(w1.y, s1f, cy1);
                cx2 = fmaf(w2.x, s2f, cx2); cy2 = fmaf(w2.y, s2f, cy2);
                cx3 = fmaf(w3.x, s3f, cx3); cy3 = fmaf(w3.y, s3f, cy3);
                cx4 = fmaf(w4.x, s4f, cx4); cy4 = fmaf(w4.y, s4f, cy4);
                cx5 = fmaf(w5.x, s5f, cx5); cy5 = fmaf(w5.y, s5f, cy5);
            }
        } else if (nmax > 0) {
            // --- SCAN path: 6 concurrent streams, exhausted -> zero row (f=-1)
            for (int n = nmax; n > 0; --n) {
                int f0 = v_ffbl(vm0); vm0 &= vm0 - 1;
                int f1 = v_ffbl(vm1); vm1 &= vm1 - 1;
                int f2 = v_ffbl(vm2); vm2 &= vm2 - 1;
                int f3 = v_ffbl(vm3); vm3 &= vm3 - 1;
                int f4 = v_ffbl(vm4); vm4 &= vm4 - 1;
                int f5 = v_ffbl(vm5); vm5 &= vm5 - 1;
                float2 w0 = *(const float2*)(gbase0 + f0 * 64);
                float2 w1 = *(const float2*)(gbase1 + f1 * 64);
                float2 w2 = *(const float2*)(gbase2 + f2 * 64);
                float2 w3 = *(const float2*)(gbase3 + f3 * 64);
                float2 w4 = *(const float2*)(gbase4 + f4 * 64);
                float2 w5 = *(const float2*)(gbase5 + f5 * 64);
                cx0 += w0.x; cy0 += w0.y;
                cx1 += w1.x; cy1 += w1.y;
                cx2 += w2.x; cy2 += w2.y;
                cx3 += w3.x; cy3 += w3.y;
                cx4 += w4.x; cy4 += w4.y;
                cx5 += w5.x; cy5 += w5.y;
            }
        }

        // Merge partials in ascending-d order
        float cx = ((((cx0 + cx1) + cx2) + cx3) + cx4) + cx5;
        float cy = ((((cy0 + cy1) + cy2) + cy3) + cy4) + cy5;
        float c1x = cx, c1y = cy;                      // step t   (lanes 0..24)
        float c2x = __shfl_down(cx, 32);               // step t+1 -> lanes 0..24
        float c2y = __shfl_down(cy, 32);

        // --- LIF layer 1, step t
        mem1x = 0.9f * mem1x + c1x;
        bool spx = (mem1x - 1.0f > 0.f) && (lane < 25);
        mem1x -= spx ? 1.0f : 0.f;
        mem1y = 0.9f * mem1y + c1y;
        bool spy = (mem1y - 1.0f > 0.f) && (lane < 25);
        mem1y -= spy ? 1.0f : 0.f;
        unsigned long long bx = __ballot(spx), by = __ballot(spy);
        unsigned long long mh_t = (bx & 0x1FFFFFFull) | ((by & 0x1FFFFFFull) << 25);
        // --- LIF layer 1, step t+1
        mem1x = 0.9f * mem1x + c2x;
        bool qx = (mem1x - 1.0f > 0.f) && (lane < 25);
        mem1x -= qx ? 1.0f : 0.f;
        mem1y = 0.9f * mem1y + c2y;
        bool qy = (mem1y - 1.0f > 0.f) && (lane < 25);
        mem1y -= qy ? 1.0f : 0.f;
        bx = __ballot(qx); by = __ballot(qy);
        unsigned long long mh_u = (bx & 0x1FFFFFFull) | ((by & 0x1FFFFFFull) << 25);

        // --- layer-2 paired gather (all-VALU): rh = __ffsll; empty -> row 0
        float cur2 = 0.f;
        int n2a = __popcll(mh_t), n2b = __popcll(mh_u);
        int n2 = n2a > n2b ? n2a : n2b;
        if (n2) {
            unsigned long long va2 = pin_v64(mh_t), vb2 = pin_v64(mh_u);
            for (; n2 > 0; --n2) {
                int fa = (int)__ffsll((unsigned long long)va2);
                int fb = (int)__ffsll((unsigned long long)vb2);
                va2 &= va2 - 1;
                vb2 &= vb2 - 1;
                int f = isLo ? fa : fb;
                cur2 += Wt2[(f << 3) + laneHalf];
            }
        }
        float c2t1 = __shfl_down(cur2, 32);            // step t+1 -> lanes 0..4

        // --- LIF layer 2, step t
        mem2 = 0.9f * mem2 + cur2;
        bool sp2 = (mem2 - 1.0f > 0.f);
        mem2 -= sp2 ? 1.0f : 0.f;
        if (active && lane < C)
            outSpk[(size_t)t * B * C + (size_t)b * C + lane] = sp2 ? 1.0f : 0.0f;
        // --- LIF layer 2, step t+1
        mem2 = 0.9f * mem2 + c2t1;
        bool sp2b = (mem2 - 1.0f > 0.f);
        mem2 -= sp2b ? 1.0f : 0.f;
        if (active && lane < C)
            outSpk[(size_t)(t + 1) * B * C + (size_t)b * C + lane] = sp2b ? 1.0f : 0.0f;
    }

    // --- reduce spike count across the wave, write counts[b]
    for (int o = 32; o; o >>= 1) cnt += __shfl_xor(cnt, o, 64);
    if (active && lane == 0) outCnt[b] = (float)cnt;
}

extern "C" void kernel_launch(void* const* d_in, const int* in_sizes, int n_in,
                              void* d_out, int out_size, void* d_ws, size_t ws_size,
                              hipStream_t stream) {
    const float* x  = (const float*)d_in[0];
    const float* W1 = (const float*)d_in[1];
    const float* W2 = (const float*)d_in[2];
    float* out = (float*)d_out;
    const int B = in_sizes[0] / D;
    const int blocks = (B + WPB - 1) / WPB;
    burst_snn_kernel<<<blocks, 1024, 0, stream>>>(x, W1, W2, out, B);
}

// Round 9
// 162.043 us; speedup vs baseline: 1.1131x; 1.1131x over previous
//
#include <hip/hip_runtime.h>

// BurstSnn: 32-step burst-encoder + 2-layer LIF SNN, B=16384, D=187, H=50, C=5.
// One wave per batch element; 16 waves/block share one LDS weight copy.
// R8 = R6 (best, 118.7us) + two changes:
//  (1) layer-2 gather in QUARTER-waves: q0..q3 scan {lo_t, hi_t, lo_u, hi_u}
//      (the LIF1 ballots bx/by are already the h<25 / h>=25 masks) -> one
//      ds_read_b32 covers 4 spikes; trips = max of 4 half-size popcounts.
//      Dedicated zero rows (0 for lo, 26 for hi) absorb exhausted quarters.
//  (2) separate per-group L1 accumulators (6 pairs, ascending merge as in R7)
//      so phase-1 reads overlap phase-0 accumulate tail.
// L1 gather unchanged from R6: 2 phases x 3 streams (groups {0,2,4}/{1,3,5}),
// half-wave t/t+1 pairing, float2 rows {h=l, h=l+25}, zero rows at rd=33g.

constexpr int D = 187;
constexpr int H = 50;
constexpr int C = 5;
constexpr int T = 32;
constexpr int WPB = 16;        // waves per block
constexpr int ROWS1 = 193;     // rows rd = 33*(d>>5) + (d&31) + 1; rd=33g zero
constexpr int RS = 64;         // floats per Wt1 row (256 B)

__device__ __forceinline__ int v_ffbl(unsigned int m) {  // -1 when m == 0
    int r;
    asm("v_ffbl_b32 %0, %1" : "=v"(r) : "v"(m));
    return r;
}

__global__ __launch_bounds__(1024, 8)
void burst_snn_kernel(const float* __restrict__ x,
                      const float* __restrict__ W1,
                      const float* __restrict__ W2,
                      float* __restrict__ out, int B) {
    // Wt1 row layout (split-pair): floats {2l,2l+1} = {W[h=l], W[h=l+25]}, l<25.
    __shared__ float Wt1[ROWS1 * RS];   // 12352 floats = 48.25 KB
    // Wt2: 64 rows x 16 floats. row 0: zeros; rows 1..25: h=0..24;
    // row 26: zeros; rows 27..51: h=25..49; rest zeros. cols 5..15 zero pad.
    __shared__ float Wt2[1024];         // 4 KB

    const int tid = threadIdx.x;
    for (int idx = tid; idx < ROWS1 * RS; idx += 1024) {
        int rd = idx >> 6, j = idx & 63;
        int g = rd / 33;
        bool zrow = (rd == 33 * g);
        int d = rd - 1 - g;
        int l = j >> 1;
        int h = (j & 1) ? (l + 25) : l;
        float v = 0.f;
        if (!zrow && l < 25) v = W1[h * D + d];
        Wt1[idx] = v;
    }
    {
        int r = tid >> 4, c = tid & 15;   // tid covers all 1024
        int h = -1;
        if (r >= 1 && r <= 25) h = r - 1;
        else if (r >= 27 && r <= 51) h = r - 2;
        float v = 0.f;
        if (h >= 0 && c < C) v = W2[c * H + h];
        Wt2[tid] = v;
    }
    __syncthreads();

    const int lane = tid & 63;
    const int b = blockIdx.x * WPB + (tid >> 6);
    const bool active = b < B;
    const bool isLo = lane < 32;
    const int laneHalf = lane & 31;
    const int laneOff2 = laneHalf * 2;   // float2 slot within a Wt1 row

    // L1 per-group base pointers, +1 row folded in: addr(f) = base + f*64;
    // f = -1 (exhausted stream) -> zero row 33g.
    const float* gbase0 = Wt1 + ((33 * 0 + 1) << 6) + laneOff2;
    const float* gbase1 = Wt1 + ((33 * 1 + 1) << 6) + laneOff2;
    const float* gbase2 = Wt1 + ((33 * 2 + 1) << 6) + laneOff2;
    const float* gbase3 = Wt1 + ((33 * 3 + 1) << 6) + laneOff2;
    const float* gbase4 = Wt1 + ((33 * 4 + 1) << 6) + laneOff2;
    const float* gbase5 = Wt1 + ((33 * 5 + 1) << 6) + laneOff2;

    // L2 quarter-wave setup: quarter q = lane>>4 scans {lo_t,hi_t,lo_u,hi_u}.
    // base row 1 (lo) / 27 (hi); f = -1 -> row 0 / 26 (zeros).
    const int q = lane >> 4;
    const bool hiQ = (q & 1) != 0;
    const float* base2 = Wt2 + ((hiQ ? 27 : 1) << 4) + (lane & 15);

    // Encoder registers: dims lane, lane+64, lane+128 (3rd valid for lane<59)
    float r0 = 0.f, r1 = 0.f, r2 = 0.f;
    if (active) {
        const float* xb = x + (size_t)b * D;
        r0 = xb[lane];
        r1 = xb[64 + lane];
        if (lane < D - 128) r2 = xb[128 + lane];
    }
    float th0 = 0.125f, th1 = 0.125f, th2 = 0.125f;
    float mem1x = 0.f, mem1y = 0.f;  // lanes 0..24: h = lane / h = lane+25
    float mem2 = 0.f;                // lanes 0..4: c = lane
    int cnt = 0;

    float* outSpk = out;                     // [T][B][C]
    float* outCnt = out + (size_t)T * B * C; // [B]

    unsigned int ga[6], gb[6];

    for (int t = 0; t < T; t += 2) {
        // --- two encoder steps (exact fp32 sequence), masks for t and t+1
        {
            bool s0 = r0 >= th0, s1 = r1 >= th1, s2 = r2 >= th2;
            r0 -= s0 ? th0 : 0.f; th0 = s0 ? th0 + th0 : 0.125f;
            r1 -= s1 ? th1 : 0.f; th1 = s1 ? th1 + th1 : 0.125f;
            r2 -= s2 ? th2 : 0.f; th2 = s2 ? th2 + th2 : 0.125f;
            cnt += (int)s0 + (int)s1 + (int)s2;
            unsigned long long B0 = __ballot(s0), B1 = __ballot(s1), B2 = __ballot(s2);
            ga[0] = (unsigned int)B0; ga[1] = (unsigned int)(B0 >> 32);
            ga[2] = (unsigned int)B1; ga[3] = (unsigned int)(B1 >> 32);
            ga[4] = (unsigned int)B2; ga[5] = (unsigned int)(B2 >> 32);
        }
        {
            bool s0 = r0 >= th0, s1 = r1 >= th1, s2 = r2 >= th2;
            r0 -= s0 ? th0 : 0.f; th0 = s0 ? th0 + th0 : 0.125f;
            r1 -= s1 ? th1 : 0.f; th1 = s1 ? th1 + th1 : 0.125f;
            r2 -= s2 ? th2 : 0.f; th2 = s2 ? th2 + th2 : 0.125f;
            cnt += (int)s0 + (int)s1 + (int)s2;
            unsigned long long B0 = __ballot(s0), B1 = __ballot(s1), B2 = __ballot(s2);
            gb[0] = (unsigned int)B0; gb[1] = (unsigned int)(B0 >> 32);
            gb[2] = (unsigned int)B1; gb[3] = (unsigned int)(B1 >> 32);
            gb[4] = (unsigned int)B2; gb[5] = (unsigned int)(B2 >> 32);
        }

        // Per-lane masks: lanes<32 step t, lanes>=32 step t+1
        unsigned int vm0 = isLo ? ga[0] : gb[0];
        unsigned int vm1 = isLo ? ga[1] : gb[1];
        unsigned int vm2 = isLo ? ga[2] : gb[2];
        unsigned int vm3 = isLo ? ga[3] : gb[3];
        unsigned int vm4 = isLo ? ga[4] : gb[4];
        unsigned int vm5 = isLo ? ga[5] : gb[5];

        float cx0 = 0.f, cy0 = 0.f, cx1 = 0.f, cy1 = 0.f, cx2 = 0.f, cy2 = 0.f;
        float cx3 = 0.f, cy3 = 0.f, cx4 = 0.f, cy4 = 0.f, cx5 = 0.f, cy5 = 0.f;

        // --- phase 0: streams over groups {0,2,4}
        {
            int n0 = __popc(ga[0]) > __popc(gb[0]) ? __popc(ga[0]) : __popc(gb[0]);
            int n2g = __popc(ga[2]) > __popc(gb[2]) ? __popc(ga[2]) : __popc(gb[2]);
            int n4 = __popc(ga[4]) > __popc(gb[4]) ? __popc(ga[4]) : __popc(gb[4]);
            int n = n0 > n2g ? n0 : n2g;
            n = n > n4 ? n : n4;
            for (; n > 0; --n) {
                int f0 = v_ffbl(vm0); vm0 &= vm0 - 1;
                int f2 = v_ffbl(vm2); vm2 &= vm2 - 1;
                int f4 = v_ffbl(vm4); vm4 &= vm4 - 1;
                float2 w0 = *(const float2*)(gbase0 + f0 * 64);
                float2 w2 = *(const float2*)(gbase2 + f2 * 64);
                float2 w4 = *(const float2*)(gbase4 + f4 * 64);
                cx0 += w0.x; cy0 += w0.y;
                cx2 += w2.x; cy2 += w2.y;
                cx4 += w4.x; cy4 += w4.y;
            }
        }
        // --- phase 1: streams over groups {1,3,5}
        {
            int n1 = __popc(ga[1]) > __popc(gb[1]) ? __popc(ga[1]) : __popc(gb[1]);
            int n3 = __popc(ga[3]) > __popc(gb[3]) ? __popc(ga[3]) : __popc(gb[3]);
            int n5 = __popc(ga[5]) > __popc(gb[5]) ? __popc(ga[5]) : __popc(gb[5]);
            int n = n1 > n3 ? n1 : n3;
            n = n > n5 ? n : n5;
            for (; n > 0; --n) {
                int f1 = v_ffbl(vm1); vm1 &= vm1 - 1;
                int f3 = v_ffbl(vm3); vm3 &= vm3 - 1;
                int f5 = v_ffbl(vm5); vm5 &= vm5 - 1;
                float2 w1 = *(const float2*)(gbase1 + f1 * 64);
                float2 w3 = *(const float2*)(gbase3 + f3 * 64);
                float2 w5 = *(const float2*)(gbase5 + f5 * 64);
                cx1 += w1.x; cy1 += w1.y;
                cx3 += w3.x; cy3 += w3.y;
                cx5 += w5.x; cy5 += w5.y;
            }
        }

        // Merge partials in ascending-d block order
        float cx = ((((cx0 + cx1) + cx2) + cx3) + cx4) + cx5;
        float cy = ((((cy0 + cy1) + cy2) + cy3) + cy4) + cy5;
        float c1x = cx, c1y = cy;                      // step t   (lanes 0..24)
        float c2x = __shfl_down(cx, 32);               // step t+1 -> lanes 0..24
        float c2y = __shfl_down(cy, 32);

        // --- LIF layer 1, step t
        mem1x = 0.9f * mem1x + c1x;
        bool spx = (mem1x - 1.0f > 0.f) && (lane < 25);
        mem1x -= spx ? 1.0f : 0.f;
        mem1y = 0.9f * mem1y + c1y;
        bool spy = (mem1y - 1.0f > 0.f) && (lane < 25);
        mem1y -= spy ? 1.0f : 0.f;
        unsigned int lo_t = (unsigned int)(__ballot(spx) & 0x1FFFFFFull); // h<25
        unsigned int hi_t = (unsigned int)(__ballot(spy) & 0x1FFFFFFull); // h>=25
        // --- LIF layer 1, step t+1
        mem1x = 0.9f * mem1x + c2x;
        bool qx = (mem1x - 1.0f > 0.f) && (lane < 25);
        mem1x -= qx ? 1.0f : 0.f;
        mem1y = 0.9f * mem1y + c2y;
        bool qy = (mem1y - 1.0f > 0.f) && (lane < 25);
        mem1y -= qy ? 1.0f : 0.f;
        unsigned int lo_u = (unsigned int)(__ballot(qx) & 0x1FFFFFFull);
        unsigned int hi_u = (unsigned int)(__ballot(qy) & 0x1FFFFFFull);

        // --- layer-2 quarter-wave gather: q0..q3 scan {lo_t,hi_t,lo_u,hi_u};
        //     one ds_read_b32 per trip covers 4 spikes; f=-1 -> zero row.
        int p0 = __popc(lo_t), p1 = __popc(hi_t), p2 = __popc(lo_u), p3 = __popc(hi_u);
        int n2 = p0 > p1 ? p0 : p1;
        n2 = n2 > p2 ? n2 : p2;
        n2 = n2 > p3 ? n2 : p3;
        float cq = 0.f;
        if (n2) {
            unsigned int vmq = isLo ? (hiQ ? hi_t : lo_t) : (hiQ ? hi_u : lo_u);
            for (; n2 > 0; --n2) {
                int f = v_ffbl(vmq); vmq &= vmq - 1;
                cq += *(base2 + f * 16);
            }
        }
        // combine quarters: lanes 0..4 get (lo+hi) for t; +32 lanes for t+1
        float tmp = cq + __shfl_down(cq, 16);
        float cur2 = tmp;                              // step t   (lanes 0..4)
        float c2t1 = __shfl_down(tmp, 32);             // step t+1 -> lanes 0..4

        // --- LIF layer 2, step t
        mem2 = 0.9f * mem2 + cur2;
        bool sp2 = (mem2 - 1.0f > 0.f);
        mem2 -= sp2 ? 1.0f : 0.f;
        if (active && lane < C)
            outSpk[(size_t)t * B * C + (size_t)b * C + lane] = sp2 ? 1.0f : 0.0f;
        // --- LIF layer 2, step t+1
        mem2 = 0.9f * mem2 + c2t1;
        bool sp2b = (mem2 - 1.0f > 0.f);
        mem2 -= sp2b ? 1.0f : 0.f;
        if (active && lane < C)
            outSpk[(size_t)(t + 1) * B * C + (size_t)b * C + lane] = sp2b ? 1.0f : 0.0f;
    }

    // --- reduce spike count across the wave, write counts[b]
    for (int o = 32; o; o >>= 1) cnt += __shfl_xor(cnt, o, 64);
    if (active && lane == 0) outCnt[b] = (float)cnt;
}

extern "C" void kernel_launch(void* const* d_in, const int* in_sizes, int n_in,
                              void* d_out, int out_size, void* d_ws, size_t ws_size,
                              hipStream_t stream) {
    const float* x  = (const float*)d_in[0];
    const float* W1 = (const float*)d_in[1];
    const float* W2 = (const float*)d_in[2];
    float* out = (float*)d_out;
    const int B = in_sizes[0] / D;
    const int blocks = (B + WPB - 1) / WPB;
    burst_snn_kernel<<<blocks, 1024, 0, stream>>>(x, W1, W2, out, B);
}